// Round 4
// baseline (177.512 us; speedup 1.0000x reference)
//
#include <hip/hip_runtime.h>

#define KK 8
#define DD 16
#define NN 32
#define TT 200
#define BB 2048

// per-k LDS slab strides, == 4 (mod 32) floats AND multiples of 4 (16-B
// alignment for float4) so the <=8 distinct per-lane k values spread
// across banks -> conflict-free ds_read_b128
#define SC 516   // C slab stride (512 used)
#define SE 36    // emission table stride (32 used)
#define SD 20    // dyn table stride (16 used)

// works for LDS or global rows: compiler infers addrspace (ds_read_b128
// vs global_load_dwordx4) from the pointer's provenance
__device__ __forceinline__ float dot16(const float* __restrict__ row,
                                       const float* __restrict__ z) {
  const float4* r4 = reinterpret_cast<const float4*>(row);
  float4 c0 = r4[0], c1 = r4[1], c2 = r4[2], c3 = r4[3];
  float a = c0.x * z[0], b = c0.y * z[1];
  a = fmaf(c0.z, z[2], a);  b = fmaf(c0.w, z[3], b);
  a = fmaf(c1.x, z[4], a);  b = fmaf(c1.y, z[5], b);
  a = fmaf(c1.z, z[6], a);  b = fmaf(c1.w, z[7], b);
  a = fmaf(c2.x, z[8], a);  b = fmaf(c2.y, z[9], b);
  a = fmaf(c2.z, z[10], a); b = fmaf(c2.w, z[11], b);
  a = fmaf(c3.x, z[12], a); b = fmaf(c3.y, z[13], b);
  a = fmaf(c3.z, z[14], a); b = fmaf(c3.w, z[15], b);
  return a + b;
}

// const-indexed register fill (keeps the array SROA-able into VGPRs)
__device__ __forceinline__ void load16(float* __restrict__ d,
                                       const float* __restrict__ s) {
  const float4* p = reinterpret_cast<const float4*>(s);
  float4 a0 = p[0], a1 = p[1], a2 = p[2], a3 = p[3];
  d[0] = a0.x;  d[1] = a0.y;  d[2] = a0.z;  d[3] = a0.w;
  d[4] = a1.x;  d[5] = a1.y;  d[6] = a1.z;  d[7] = a1.w;
  d[8] = a2.x;  d[9] = a2.y;  d[10] = a2.z; d[11] = a2.w;
  d[12] = a3.x; d[13] = a3.y; d[14] = a3.z; d[15] = a3.w;
}

// PIPE LEDGER (the round-4 theory): per item-wave-batch the old kernel
// issued 216 ds_read_b128 (~12 cyc each, m134) -> ~27 us/CU LDS-pipe floor
// at 25 batches/CU; measured 42 us -> LDS-bound. This version moves A
// (8 KB, permanently L1/L2-hot) and the rare init tables OFF the LDS pipe
// onto the near-idle VMEM pipe: LDS instr/item 216 -> 152 (C 128 + em 16
// + dyn 8), floor ~19 us, VMEM ~82 instr/item on a separate pipe.
// OCCUPANCY LEDGER: VGPR 65..128 is one equivalence class (waves/CU
// halve at 64/128 -- m69) -> 16 waves/CU -> 4 blocks/CU resident. Grid is
// therefore 1024 blocks x 400 items: EXACTLY 4/CU, uniform, single round
// (round-3's 5/CU demand on 4-resident ran a 25% single-block tail).
// LDS total 20448 B (sA + init tables gone) no longer caps residency.
__global__ __launch_bounds__(256) void slds_lp_kernel(
    const int* __restrict__ dsts,      // [B,T]
    const float* __restrict__ zg,      // [B,T,D]
    const float* __restrict__ obsg,    // [B,T,N]
    const float* __restrict__ initlg,  // [K]
    const float* __restrict__ initloc, // [K,D]
    const float* __restrict__ initls,  // [K,D]
    const float* __restrict__ transg,  // [K,K]
    const float* __restrict__ Ag,      // [K,D,D]
    const float* __restrict__ dynoff,  // [K,D]
    const float* __restrict__ dynls,   // [K,D] (scale directly, NOT log)
    const float* __restrict__ Cg,      // [K,N,D]
    const float* __restrict__ emoff,   // [K,N]
    const float* __restrict__ emls,    // [K,N]
    float* __restrict__ out)           // [B]
{
  __shared__ __align__(16) float sC[KK * SC];
  __shared__ __align__(16) float sEmOff[KK * SE];
  __shared__ __align__(16) float sEmInv[KK * SE];
  __shared__ __align__(16) float sDynOff[KK * SD];
  __shared__ __align__(16) float sDynInv[KK * SD];
  __shared__ float sTrans[KK * KK];
  __shared__ float sEmConst[KK];
  __shared__ float sDynConst[KK];
  __shared__ float sInitLp[KK];

  const float HALF_LOG2PI = 0.91893853320467274178f;
  const int tid = threadIdx.x;

  // ---- stage params into LDS (transforms applied once per block) ----
  for (int i = tid; i < KK * NN * DD; i += 256) {   // 4096
    int k = i >> 9, r = i & 511;
    sC[k * SC + r] = Cg[i];
  }
  if (tid < KK * NN) {                              // 256
    int k = tid >> 5, n = tid & 31;
    sEmOff[k * SE + n] = emoff[tid];
    sEmInv[k * SE + n] = expf(-emls[tid]);
  }
  if (tid < KK * DD) {                              // 128
    int k = tid >> 4, d = tid & 15;
    sDynOff[k * SD + d] = dynoff[tid];
    sDynInv[k * SD + d] = 1.0f / dynls[tid];
  }
  if (tid < KK * KK) {                              // 64: transition log-softmax
    int kr = tid >> 3;
    float mx = transg[kr * KK];
    for (int j = 1; j < KK; ++j) mx = fmaxf(mx, transg[kr * KK + j]);
    float ss = 0.f;
    for (int j = 0; j < KK; ++j) ss += expf(transg[kr * KK + j] - mx);
    sTrans[tid] = transg[tid] - (logf(ss) + mx);
  }
  if (tid < KK) {                                   // per-k constants
    int k = tid;
    float se = 0.f;
    for (int n = 0; n < NN; ++n) se -= emls[k * NN + n];
    sEmConst[k] = se - NN * HALF_LOG2PI;
    float sd = 0.f;
    for (int d = 0; d < DD; ++d) sd -= logf(dynls[k * DD + d]);
    sDynConst[k] = sd - DD * HALF_LOG2PI;
    float mx = initlg[0];
    for (int j = 1; j < KK; ++j) mx = fmaxf(mx, initlg[j]);
    float ss = 0.f;
    for (int j = 0; j < KK; ++j) ss += expf(initlg[j] - mx);
    float si = 0.f;
    for (int d = 0; d < DD; ++d) si -= initls[k * DD + d];
    sInitLp[k] = initlg[k] - (logf(ss) + mx) + si - DD * HALF_LOG2PI;
  }
  __syncthreads();

  // ---- block bk owns items [bk*400, bk*400+400) == exactly 2 batch
  //      elements (b = 2bk, 2bk+1). Pass 1: all 256 threads; pass 2:
  //      tid < 144 (waves 2-3 mostly/fully skip via execz). ----
  const int base = blockIdx.x * 400;
  for (int ofs = tid; ofs < 400; ofs += 256) {
    const int item = base + ofs;
    const int b = item / TT;
    const int t = item - b * TT;

    float z[16];
    load16(z, zg + (size_t)item * DD);
    const int s = dsts[item];
    float lp;

    // ---- dynamics / init FIRST (zp dies before the emission loop) ----
    if (t != 0) {
      const int sp = dsts[item - 1];
      float zp[16];
      load16(zp, zg + (size_t)(item - 1) * DD);
      const float* __restrict__ Ab = Ag + (size_t)s * (DD * DD);  // global, L1/L2-hot
      const int db4 = s * (SD / 4);
      float a2acc = 0.f;
      // FULL unroll: compile-time indices keep z/zp in VGPRs (rule #20)
#pragma unroll
      for (int g = 0; g < 4; ++g) {
        const int i0 = g * 4;
        float4 off = reinterpret_cast<const float4*>(sDynOff)[db4 + g];
        float4 inv = reinterpret_cast<const float4*>(sDynInv)[db4 + g];
        float l0 = dot16(&Ab[(i0 + 0) * DD], zp) + off.x;
        float l1 = dot16(&Ab[(i0 + 1) * DD], zp) + off.y;
        float l2 = dot16(&Ab[(i0 + 2) * DD], zp) + off.z;
        float l3 = dot16(&Ab[(i0 + 3) * DD], zp) + off.w;
        float d0 = (z[i0 + 0] - l0) * inv.x;
        float d1 = (z[i0 + 1] - l1) * inv.y;
        float d2 = (z[i0 + 2] - l2) * inv.z;
        float d3 = (z[i0 + 3] - l3) * inv.w;
        a2acc = fmaf(d0, d0, a2acc); a2acc = fmaf(d1, d1, a2acc);
        a2acc = fmaf(d2, d2, a2acc); a2acc = fmaf(d3, d3, a2acc);
      }
      lp = -0.5f * a2acc + sDynConst[s] + sTrans[sp * KK + s];
    } else {
      // rare (1/200): init tables straight from global + per-item expf
      // (same inputs, same formula -> bit-identical to the staged version)
      const float* __restrict__ ploc = initloc + s * DD;
      const float* __restrict__ pls  = initls + s * DD;
      float a2acc = 0.f;
#pragma unroll
      for (int g = 0; g < 4; ++g) {
        const int i0 = g * 4;
        float4 loc = reinterpret_cast<const float4*>(ploc)[g];
        float4 ls  = reinterpret_cast<const float4*>(pls)[g];
        float d0 = (z[i0 + 0] - loc.x) * expf(-ls.x);
        float d1 = (z[i0 + 1] - loc.y) * expf(-ls.y);
        float d2 = (z[i0 + 2] - loc.z) * expf(-ls.z);
        float d3 = (z[i0 + 3] - loc.w) * expf(-ls.w);
        a2acc = fmaf(d0, d0, a2acc); a2acc = fmaf(d1, d1, a2acc);
        a2acc = fmaf(d2, d2, a2acc); a2acc = fmaf(d3, d3, a2acc);
      }
      lp = -0.5f * a2acc + sInitLp[s];
    }

    // ---- emissions (C stays in LDS -- the true reuse case) ----
    {
      const float4* o4 = reinterpret_cast<const float4*>(obsg + (size_t)item * NN);
      const int cb = s * SC;
      const int eb4 = s * (SE / 4);
      float acc = 0.f;
#pragma unroll 1
      for (int g = 0; g < 8; ++g) {
        float4 o = o4[g];
        float4 off = reinterpret_cast<const float4*>(sEmOff)[eb4 + g];
        float4 inv = reinterpret_cast<const float4*>(sEmInv)[eb4 + g];
        int n0 = g * 4;
        float l0 = dot16(&sC[cb + (n0 + 0) * DD], z) + off.x;
        float l1 = dot16(&sC[cb + (n0 + 1) * DD], z) + off.y;
        float l2 = dot16(&sC[cb + (n0 + 2) * DD], z) + off.z;
        float l3 = dot16(&sC[cb + (n0 + 3) * DD], z) + off.w;
        float d0 = (o.x - l0) * inv.x;
        float d1 = (o.y - l1) * inv.y;
        float d2 = (o.z - l2) * inv.z;
        float d3 = (o.w - l3) * inv.w;
        acc = fmaf(d0, d0, acc); acc = fmaf(d1, d1, acc);
        acc = fmaf(d2, d2, acc); acc = fmaf(d3, d3, acc);
      }
      lp += -0.5f * acc + sEmConst[s];
    }

    // ---- wave-level segmented sum keyed by b, then atomic.
    //      ofs==399 guards the pass-2 partial wave (next lane inactive
    //      -> shfl_down returns garbage b; without the guard the last
    //      active lane could skip its atomic). ----
    const int lane = tid & 63;
    float v = lp;
#pragma unroll
    for (int off = 1; off < 64; off <<= 1) {
      float ov = __shfl_up(v, off, 64);
      int obk = __shfl_up(b, off, 64);
      if (lane >= off && obk == b) v += ov;
    }
    int nb = __shfl_down(b, 1, 64);
    if (lane == 63 || ofs == 399 || nb != b) atomicAdd(&out[b], v);
  }
}

extern "C" void kernel_launch(void* const* d_in, const int* in_sizes, int n_in,
                              void* d_out, int out_size, void* d_ws, size_t ws_size,
                              hipStream_t stream) {
  const int*   dsts    = (const int*)d_in[0];
  const float* zg      = (const float*)d_in[1];
  const float* obsg    = (const float*)d_in[2];
  const float* initlg  = (const float*)d_in[3];
  const float* initloc = (const float*)d_in[4];
  const float* initls  = (const float*)d_in[5];
  const float* transg  = (const float*)d_in[6];
  const float* Ag      = (const float*)d_in[7];
  const float* dynoff  = (const float*)d_in[8];
  const float* dynls   = (const float*)d_in[9];
  const float* Cg      = (const float*)d_in[10];
  const float* emoff   = (const float*)d_in[11];
  const float* emls    = (const float*)d_in[12];
  float* out = (float*)d_out;

  hipMemsetAsync(d_out, 0, BB * sizeof(float), stream);

  // 1024 blocks x 400 items each == exactly B*T; uniform 4 blocks/CU
  // (matches the 65..128-VGPR residency class), single round, no tail
  slds_lp_kernel<<<1024, 256, 0, stream>>>(dsts, zg, obsg, initlg, initloc,
                                           initls, transg, Ag, dynoff, dynls,
                                           Cg, emoff, emls, out);
}

// Round 5
// 139.937 us; speedup vs baseline: 1.2685x; 1.2685x over previous
//
#include <hip/hip_runtime.h>

#define KK 8
#define DD 16
#define NN 32
#define TT 200
#define BB 2048

// per-k LDS slab strides, == 4 (mod 32) floats AND multiples of 4 (16-B
// alignment for float4) so the <=8 distinct per-lane k values spread
// across banks -> conflict-free (broadcast) ds_read_b128
#define SC 516   // C slab stride (512 used)
#define SA 260   // A slab stride (256 used)
#define SE 36    // emission table stride (32 used)
#define SD 20    // dyn table stride (16 used)

__device__ __forceinline__ float dot16(const float* __restrict__ row,
                                       const float* __restrict__ z) {
  const float4* r4 = reinterpret_cast<const float4*>(row);
  float4 c0 = r4[0], c1 = r4[1], c2 = r4[2], c3 = r4[3];
  float a = c0.x * z[0], b = c0.y * z[1];
  a = fmaf(c0.z, z[2], a);  b = fmaf(c0.w, z[3], b);
  a = fmaf(c1.x, z[4], a);  b = fmaf(c1.y, z[5], b);
  a = fmaf(c1.z, z[6], a);  b = fmaf(c1.w, z[7], b);
  a = fmaf(c2.x, z[8], a);  b = fmaf(c2.y, z[9], b);
  a = fmaf(c2.z, z[10], a); b = fmaf(c2.w, z[11], b);
  a = fmaf(c3.x, z[12], a); b = fmaf(c3.y, z[13], b);
  a = fmaf(c3.z, z[14], a); b = fmaf(c3.w, z[15], b);
  return a + b;
}

// const-indexed register fill (keeps the array SROA-able into VGPRs)
__device__ __forceinline__ void load16(float* __restrict__ d,
                                       const float* __restrict__ s) {
  const float4* p = reinterpret_cast<const float4*>(s);
  float4 a0 = p[0], a1 = p[1], a2 = p[2], a3 = p[3];
  d[0] = a0.x;  d[1] = a0.y;  d[2] = a0.z;  d[3] = a0.w;
  d[4] = a1.x;  d[5] = a1.y;  d[6] = a1.z;  d[7] = a1.w;
  d[8] = a2.x;  d[9] = a2.y;  d[10] = a2.z; d[11] = a2.w;
  d[12] = a3.x; d[13] = a3.y; d[14] = a3.z; d[15] = a3.w;
}

// OCCUPANCY LEDGER (round-5 theory: the kernel is LATENCY-bound; the LDS
// "floor" was wrong -- <=8 distinct per-lane addresses broadcast, so a
// b128 read moves ~128 B not 1 KB). Residency per CU = min(2048 threads,
// LDS, VGPR class). 512-thread blocks: 4 blocks/CU == the 2048-thread cap;
// LDS 4 x 28.8 KB = 115 KB <= 160 OK; VGPR <= 64 (round-4's body measured
// 60) -> 8 waves/SIMD -> all 32 waves/CU resident, 2x round-3's 16.
// Grid 1024 x 400 items, single pass (tid < 400; waves 7 retires at once,
// wave 6 is 16/64 active) -> ~25 work-active waves/CU, uniform, one round.
// A stays in LDS (round-4 proved global-A's 114-200cy chain is fatal at
// low wave count); LDS addressing is 32-bit -> fewer addr regs than global.
// Init path stays global+expf (1/200 items, bit-identical formula).
__global__ __launch_bounds__(512) void slds_lp_kernel(
    const int* __restrict__ dsts,      // [B,T]
    const float* __restrict__ zg,      // [B,T,D]
    const float* __restrict__ obsg,    // [B,T,N]
    const float* __restrict__ initlg,  // [K]
    const float* __restrict__ initloc, // [K,D]
    const float* __restrict__ initls,  // [K,D]
    const float* __restrict__ transg,  // [K,K]
    const float* __restrict__ Ag,      // [K,D,D]
    const float* __restrict__ dynoff,  // [K,D]
    const float* __restrict__ dynls,   // [K,D] (scale directly, NOT log)
    const float* __restrict__ Cg,      // [K,N,D]
    const float* __restrict__ emoff,   // [K,N]
    const float* __restrict__ emls,    // [K,N]
    float* __restrict__ out)           // [B]
{
  __shared__ __align__(16) float sC[KK * SC];
  __shared__ __align__(16) float sA[KK * SA];
  __shared__ __align__(16) float sEmOff[KK * SE];
  __shared__ __align__(16) float sEmInv[KK * SE];
  __shared__ __align__(16) float sDynOff[KK * SD];
  __shared__ __align__(16) float sDynInv[KK * SD];
  __shared__ float sTrans[KK * KK];
  __shared__ float sEmConst[KK];
  __shared__ float sDynConst[KK];
  __shared__ float sInitLp[KK];

  const float HALF_LOG2PI = 0.91893853320467274178f;
  const int tid = threadIdx.x;

  // ---- stage params into LDS (transforms applied once per block) ----
  for (int i = tid; i < KK * NN * DD; i += 512) {   // 4096
    int k = i >> 9, r = i & 511;
    sC[k * SC + r] = Cg[i];
  }
  for (int i = tid; i < KK * DD * DD; i += 512) {   // 2048
    int k = i >> 8, r = i & 255;
    sA[k * SA + r] = Ag[i];
  }
  if (tid < KK * NN) {                              // 256
    int k = tid >> 5, n = tid & 31;
    sEmOff[k * SE + n] = emoff[tid];
    sEmInv[k * SE + n] = expf(-emls[tid]);
  }
  if (tid < KK * DD) {                              // 128
    int k = tid >> 4, d = tid & 15;
    sDynOff[k * SD + d] = dynoff[tid];
    sDynInv[k * SD + d] = 1.0f / dynls[tid];
  }
  if (tid < KK * KK) {                              // 64: transition log-softmax
    int kr = tid >> 3;
    float mx = transg[kr * KK];
    for (int j = 1; j < KK; ++j) mx = fmaxf(mx, transg[kr * KK + j]);
    float ss = 0.f;
    for (int j = 0; j < KK; ++j) ss += expf(transg[kr * KK + j] - mx);
    sTrans[tid] = transg[tid] - (logf(ss) + mx);
  }
  if (tid < KK) {                                   // per-k constants
    int k = tid;
    float se = 0.f;
    for (int n = 0; n < NN; ++n) se -= emls[k * NN + n];
    sEmConst[k] = se - NN * HALF_LOG2PI;
    float sd = 0.f;
    for (int d = 0; d < DD; ++d) sd -= logf(dynls[k * DD + d]);
    sDynConst[k] = sd - DD * HALF_LOG2PI;
    float mx = initlg[0];
    for (int j = 1; j < KK; ++j) mx = fmaxf(mx, initlg[j]);
    float ss = 0.f;
    for (int j = 0; j < KK; ++j) ss += expf(initlg[j] - mx);
    float si = 0.f;
    for (int d = 0; d < DD; ++d) si -= initls[k * DD + d];
    sInitLp[k] = initlg[k] - (logf(ss) + mx) + si - DD * HALF_LOG2PI;
  }
  __syncthreads();

  // ---- block bk owns items [bk*400, bk*400+400) == exactly 2 batch
  //      elements; single pass, one item per thread, tid 400..511 idle ----
  if (tid < 400) {
    const int item = blockIdx.x * 400 + tid;
    const int b = item / TT;
    const int t = item - b * TT;

    float z[16];
    load16(z, zg + (size_t)item * DD);
    const int s = dsts[item];
    float lp;

    // ---- dynamics / init FIRST (zp dies before the emission loop) ----
    if (t != 0) {
      const int sp = dsts[item - 1];
      float zp[16];
      load16(zp, zg + (size_t)(item - 1) * DD);
      const float* __restrict__ Ab = &sA[s * SA];   // LDS, broadcast reads
      const int db4 = s * (SD / 4);
      float a2acc = 0.f;
      // FULL unroll: compile-time indices keep z/zp in VGPRs (rule #20)
#pragma unroll
      for (int g = 0; g < 4; ++g) {
        const int i0 = g * 4;
        float4 off = reinterpret_cast<const float4*>(sDynOff)[db4 + g];
        float4 inv = reinterpret_cast<const float4*>(sDynInv)[db4 + g];
        float l0 = dot16(&Ab[(i0 + 0) * DD], zp) + off.x;
        float l1 = dot16(&Ab[(i0 + 1) * DD], zp) + off.y;
        float l2 = dot16(&Ab[(i0 + 2) * DD], zp) + off.z;
        float l3 = dot16(&Ab[(i0 + 3) * DD], zp) + off.w;
        float d0 = (z[i0 + 0] - l0) * inv.x;
        float d1 = (z[i0 + 1] - l1) * inv.y;
        float d2 = (z[i0 + 2] - l2) * inv.z;
        float d3 = (z[i0 + 3] - l3) * inv.w;
        a2acc = fmaf(d0, d0, a2acc); a2acc = fmaf(d1, d1, a2acc);
        a2acc = fmaf(d2, d2, a2acc); a2acc = fmaf(d3, d3, a2acc);
      }
      lp = -0.5f * a2acc + sDynConst[s] + sTrans[sp * KK + s];
    } else {
      // rare (1/200): init tables straight from global + per-item expf
      // (same inputs, same formula -> bit-identical to staged version)
      const float* __restrict__ ploc = initloc + s * DD;
      const float* __restrict__ pls  = initls + s * DD;
      float a2acc = 0.f;
#pragma unroll
      for (int g = 0; g < 4; ++g) {
        const int i0 = g * 4;
        float4 loc = reinterpret_cast<const float4*>(ploc)[g];
        float4 ls  = reinterpret_cast<const float4*>(pls)[g];
        float d0 = (z[i0 + 0] - loc.x) * expf(-ls.x);
        float d1 = (z[i0 + 1] - loc.y) * expf(-ls.y);
        float d2 = (z[i0 + 2] - loc.z) * expf(-ls.z);
        float d3 = (z[i0 + 3] - loc.w) * expf(-ls.w);
        a2acc = fmaf(d0, d0, a2acc); a2acc = fmaf(d1, d1, a2acc);
        a2acc = fmaf(d2, d2, a2acc); a2acc = fmaf(d3, d3, a2acc);
      }
      lp = -0.5f * a2acc + sInitLp[s];
    }

    // ---- emissions (C in LDS -- the true reuse case) ----
    {
      const float4* o4 = reinterpret_cast<const float4*>(obsg + (size_t)item * NN);
      const int cb = s * SC;
      const int eb4 = s * (SE / 4);
      float acc = 0.f;
#pragma unroll 1
      for (int g = 0; g < 8; ++g) {
        float4 o = o4[g];
        float4 off = reinterpret_cast<const float4*>(sEmOff)[eb4 + g];
        float4 inv = reinterpret_cast<const float4*>(sEmInv)[eb4 + g];
        int n0 = g * 4;
        float l0 = dot16(&sC[cb + (n0 + 0) * DD], z) + off.x;
        float l1 = dot16(&sC[cb + (n0 + 1) * DD], z) + off.y;
        float l2 = dot16(&sC[cb + (n0 + 2) * DD], z) + off.z;
        float l3 = dot16(&sC[cb + (n0 + 3) * DD], z) + off.w;
        float d0 = (o.x - l0) * inv.x;
        float d1 = (o.y - l1) * inv.y;
        float d2 = (o.z - l2) * inv.z;
        float d3 = (o.w - l3) * inv.w;
        acc = fmaf(d0, d0, acc); acc = fmaf(d1, d1, acc);
        acc = fmaf(d2, d2, acc); acc = fmaf(d3, d3, acc);
      }
      lp += -0.5f * acc + sEmConst[s];
    }

    // ---- wave-level segmented sum keyed by b, then atomic.
    //      tid==399 guards the partial wave (lane 15 of wave 6 reads an
    //      inactive lane via shfl_down -> garbage nb; force its atomic). ----
    const int lane = tid & 63;
    float v = lp;
#pragma unroll
    for (int off = 1; off < 64; off <<= 1) {
      float ov = __shfl_up(v, off, 64);
      int obk = __shfl_up(b, off, 64);
      if (lane >= off && obk == b) v += ov;
    }
    int nb = __shfl_down(b, 1, 64);
    if (lane == 63 || tid == 399 || nb != b) atomicAdd(&out[b], v);
  }
}

extern "C" void kernel_launch(void* const* d_in, const int* in_sizes, int n_in,
                              void* d_out, int out_size, void* d_ws, size_t ws_size,
                              hipStream_t stream) {
  const int*   dsts    = (const int*)d_in[0];
  const float* zg      = (const float*)d_in[1];
  const float* obsg    = (const float*)d_in[2];
  const float* initlg  = (const float*)d_in[3];
  const float* initloc = (const float*)d_in[4];
  const float* initls  = (const float*)d_in[5];
  const float* transg  = (const float*)d_in[6];
  const float* Ag      = (const float*)d_in[7];
  const float* dynoff  = (const float*)d_in[8];
  const float* dynls   = (const float*)d_in[9];
  const float* Cg      = (const float*)d_in[10];
  const float* emoff   = (const float*)d_in[11];
  const float* emls    = (const float*)d_in[12];
  float* out = (float*)d_out;

  hipMemsetAsync(d_out, 0, BB * sizeof(float), stream);

  // 1024 blocks x 512 threads, 400 items each == exactly B*T.
  // 4 blocks/CU (2048-thread cap), 32 waves/CU resident if VGPR<=64.
  slds_lp_kernel<<<1024, 512, 0, stream>>>(dsts, zg, obsg, initlg, initloc,
                                           initls, transg, Ag, dynoff, dynls,
                                           Cg, emoff, emls, out);
}